// Round 11
// baseline (147.216 us; speedup 1.0000x reference)
//
#include <hip/hip_runtime.h>
#include <hip/hip_bf16.h>

#define NN 4096
#define IN_DIM 512
#define OUT_DIM 256
#define NH 4
#define HD 64
#define NEG_SLOPE 0.2f
#define LN_EPS 1e-5f
#define LOG2E 1.4426950408889634f
#define DBIAS 1024.0f

typedef __attribute__((ext_vector_type(8))) short short8;
typedef __attribute__((ext_vector_type(4))) float f32x4;
typedef unsigned short u16;
typedef unsigned int u32;
typedef unsigned char u8;

// ---------------------------------------------------------------------------
// K0: pack (adj>0)|I into bitmask [NN][NN/8 B]; blocks < 128 also transpose
// W [H][K][D] f32 -> Wt [h*64+d][512] bf16. Block 0 zeroes maxd_u and the
// per-i-tile merge counters (re-zeroed every launch -> replay-deterministic).
// ---------------------------------------------------------------------------
__global__ __launch_bounds__(1024) void k0_pack(
    const int* __restrict__ adj, u8* __restrict__ mask,
    const float* __restrict__ W, u16* __restrict__ Wt,
    u32* __restrict__ maxd_u, int* __restrict__ cnt)
{
  const int b = blockIdx.x;
  const int t = threadIdx.x;
  if (b == 0) {
    if (t < NH) maxd_u[t] = 0u;
    if (t >= 32 && t < 48) cnt[t - 32] = 0;
  }
#pragma unroll
  for (int it = 0; it < 4; ++it) {
    const int row = b * 8 + it * 2 + (t >> 9);
    const int byte = t & 511;
    const int j0 = byte * 8;
    const int4 v0 = *reinterpret_cast<const int4*>(adj + (size_t)row * NN + j0);
    const int4 v1 = *reinterpret_cast<const int4*>(adj + (size_t)row * NN + j0 + 4);
    const int vv[8] = {v0.x, v0.y, v0.z, v0.w, v1.x, v1.y, v1.z, v1.w};
    u32 bbits = 0;
#pragma unroll
    for (int c = 0; c < 8; ++c)
      if ((vv[c] > 0) || (row == j0 + c)) bbits |= (1u << c);
    mask[(size_t)row * (NN / 8) + byte] = (u8)bbits;
  }
  if (b < 128) {
    const int n = b * 1024 + t;      // n = h*2^15 + k*2^6 + d
    const int d = n & 63;
    const int k = (n >> 6) & 511;
    const int h = n >> 15;
    __hip_bfloat16 bv = __float2bfloat16(W[n]);
    Wt[(size_t)(h * HD + d) * IN_DIM + k] = *reinterpret_cast<const u16*>(&bv);
  }
}

// ---------------------------------------------------------------------------
// K1: MFMA projection, L2-direct B loads (round-7 structure), dh-split to
// 8 waves for TLP. grid 256 (16-row tiles), block 512 = 8 waves:
// wave = (dh = wv>>2 -> d cols dh*32..+32, h = wv&3). Stage x[16][512] bf16
// in LDS (XOR-swizzled), 1 barrier; 16 K-steps {1 A ds_read_b128 +
// 2 B 16B L2 loads + 2 MFMA}. Scores: per-wave 32-d partial dots, tiny LDS
// merge across dh; dh=0 stores + atomicMax maxd. LDS ~17 KB, 2-4 blocks/CU.
// ---------------------------------------------------------------------------
__global__ __launch_bounds__(512) void k1_proj(
    const float* __restrict__ x, const u16* __restrict__ Wt,
    const float* __restrict__ a,
    u16* __restrict__ WxT,
    float* __restrict__ s_src,
    float* __restrict__ d_dst,
    u32* __restrict__ maxd_u)
{
  const int i0 = blockIdx.x * 16;
  const int t = threadIdx.x;
  const int wv = t >> 6;
  const int h = wv & 3;
  const int dh = wv >> 2;        // 0..1: d-half
  const int lane = t & 63;
  const int rloc = lane & 15;
  const int g = lane >> 4;

  __shared__ u16 xl[16 * 512];        // 16 KiB, XOR-swizzled 16B units
  __shared__ float sred_s[4][16];     // dh=1 score partials
  __shared__ float sred_d[4][16];

  // ---- stage x tile: 1024 (row,unit) pairs over 512 threads x 2 passes ----
#pragma unroll
  for (int p = 0; p < 2; ++p) {
    const int n = p * 512 + t;
    const int r = n >> 6;
    const int u = n & 63;
    const float* xr = x + (size_t)(i0 + r) * IN_DIM + u * 8;
    const float4 lo = *reinterpret_cast<const float4*>(xr);
    const float4 hi = *reinterpret_cast<const float4*>(xr + 4);
    const float fv[8] = {lo.x, lo.y, lo.z, lo.w, hi.x, hi.y, hi.z, hi.w};
    u16 us[8];
#pragma unroll
    for (int e = 0; e < 8; ++e) {
      __hip_bfloat16 bv = __float2bfloat16(fv[e]);
      us[e] = *reinterpret_cast<const u16*>(&bv);
    }
    const int phys = (u & 56) | ((u & 7) ^ (r & 7));
    uint4 pk;
    pk.x = (u32)us[0] | ((u32)us[1] << 16);
    pk.y = (u32)us[2] | ((u32)us[3] << 16);
    pk.z = (u32)us[4] | ((u32)us[5] << 16);
    pk.w = (u32)us[6] | ((u32)us[7] << 16);
    *reinterpret_cast<uint4*>(&xl[r * 512 + phys * 8]) = pk;
  }
  __syncthreads();

  // ---- MFMA loop: 16 rows x 32 cols per wave, B direct from L2 ----
  f32x4 acc[2] = {};
  const u16* wb = Wt + (size_t)(h * HD + dh * 32 + rloc) * IN_DIM;
#pragma unroll
  for (int ks = 0; ks < 16; ++ks) {
    const int u = ks * 4 + g;
    const int aphys = (u & 56) | ((u & 7) ^ (rloc & 7));
    const short8 af = *reinterpret_cast<const short8*>(&xl[rloc * 512 + aphys * 8]);
#pragma unroll
    for (int d2 = 0; d2 < 2; ++d2) {
      const short8 bf = *reinterpret_cast<const short8*>(
          wb + (size_t)d2 * 16 * IN_DIM + ks * 32 + g * 8);
      acc[d2] = __builtin_amdgcn_mfma_f32_16x16x32_bf16(af, bf, acc[d2], 0, 0, 0);
    }
  }

  // ---- WxT store (acc[d2][q] = C[i=i0+g*4+q][d=dh*32+d2*16+rloc]) ----
#pragma unroll
  for (int d2 = 0; d2 < 2; ++d2) {
    u16 us[4];
#pragma unroll
    for (int q = 0; q < 4; ++q) {
      __hip_bfloat16 bv = __float2bfloat16(acc[d2][q]);
      us[q] = *reinterpret_cast<const u16*>(&bv);
    }
    ushort4 pk = {us[0], us[1], us[2], us[3]};
    *reinterpret_cast<ushort4*>(
        WxT + (size_t)(h * HD + dh * 32 + d2 * 16 + rloc) * NN + i0 + g * 4) = pk;
  }

  // ---- score partial dots over this wave's 32 d's ----
  float as_v[2], ad_v[2];
#pragma unroll
  for (int d2 = 0; d2 < 2; ++d2) {
    as_v[d2] = a[(size_t)h * 2 * HD + dh * 32 + d2 * 16 + rloc];
    ad_v[d2] = a[(size_t)h * 2 * HD + HD + dh * 32 + d2 * 16 + rloc];
  }
  float sv[4], dv[4];
#pragma unroll
  for (int q = 0; q < 4; ++q) {
    float s = 0.f, d = 0.f;
#pragma unroll
    for (int d2 = 0; d2 < 2; ++d2) {
      s = fmaf(acc[d2][q], as_v[d2], s);
      d = fmaf(acc[d2][q], ad_v[d2], d);
    }
    sv[q] = s; dv[q] = d;
  }
#pragma unroll
  for (int mm = 8; mm >= 1; mm >>= 1) {
#pragma unroll
    for (int q = 0; q < 4; ++q) {
      sv[q] += __shfl_xor(sv[q], mm);
      dv[q] += __shfl_xor(dv[q], mm);
    }
  }
  if (dh == 1 && rloc == 0) {
#pragma unroll
    for (int q = 0; q < 4; ++q) {
      sred_s[h][g * 4 + q] = sv[q];
      sred_d[h][g * 4 + q] = dv[q];
    }
  }
  __syncthreads();
  if (dh == 0) {
    float dtt[4];
#pragma unroll
    for (int q = 0; q < 4; ++q) {
      const int row = g * 4 + q;
      const float st = sv[q] + sred_s[h][row];
      dtt[q] = dv[q] + sred_d[h][row];
      if (rloc == 0) {
        s_src[(size_t)h * NN + i0 + row] = st * LOG2E;
        d_dst[(size_t)h * NN + i0 + row] = dtt[q] * LOG2E;
      }
    }
    float dm = fmaxf(fmaxf(dtt[0], dtt[1]), fmaxf(dtt[2], dtt[3])) * LOG2E + DBIAS;
#pragma unroll
    for (int mm = 8; mm >= 1; mm >>= 1) dm = fmaxf(dm, __shfl_xor(dm, mm));
    if (rloc == 0) atomicMax(maxd_u + h, __float_as_uint(dm));
  }
}

// ---------------------------------------------------------------------------
// K3: masked rank-1 softmax (log2 domain) + PV (bf16 MFMA), LDS-staged &
// double-buffered [round-8 verified interior]. grid (16 i-blocks, 4 heads,
// 4 j-quarters), block 512 = 8 waves x 32 rows. FUSED FINALE: the 16th
// block finishing an i-tile (atomicAdd counter, rocPRIM last-block pattern)
// merges the 4 jq partials, normalizes, ELU, LayerNorm, stores out.
// ---------------------------------------------------------------------------
__global__ __launch_bounds__(512) void k3_attn(
    const u8* __restrict__ mask,
    const u16* __restrict__ WxT,
    const float* __restrict__ s_src, const float* __restrict__ d_dst,
    const u32* __restrict__ maxd_u,
    u16* __restrict__ Pp, float* __restrict__ Sp,
    const float* __restrict__ gamma, const float* __restrict__ beta,
    float* __restrict__ out, int* __restrict__ cnt)
{
  const int bx = blockIdx.x;
  const int h = blockIdx.y;
  const int jq = blockIdx.z;
  const int t = threadIdx.x;
  const int wv = t >> 6;
  const int lane = t & 63;
  const int rloc = lane & 15;
  const int g = lane >> 4;
  const int i_base = bx * 256 + wv * 32;

  __shared__ u16 wt[2][64 * 128];   // [buf][row*128 + unit*8], XOR-swizzled
  __shared__ u32 mk[256 * 36];      // [row][36 words] (32 used, pad 4)
  __shared__ int last_flag;

  const float md = __uint_as_float(maxd_u[h]) - DBIAS;
  const float si0 = s_src[(size_t)h * NN + i_base + rloc];
  const float si1 = s_src[(size_t)h * NN + i_base + 16 + rloc];
  const float e00 = si0 + md, e01 = si1 + md;
  const float m0 = fmaxf(e00, NEG_SLOPE * e00);
  const float m1 = fmaxf(e01, NEG_SLOPE * e01);
  const float sa0 = si0 - m0, sb0 = fmaf(NEG_SLOPE, si0, -m0);
  const float sa1 = si1 - m1, sb1 = fmaf(NEG_SLOPE, si1, -m1);

  const float* dg = d_dst + (size_t)h * NN + jq * 1024;
  const u16* wsrc = WxT + (size_t)(h * HD) * NN + jq * 1024;

  const int r0 = t >> 4;
  const int un = t & 15;
  const int up = un ^ (r0 & 7);

#pragma unroll
  for (int k = 0; k < 4; ++k) {
    const int n = k * 512 + t;
    const int row = n >> 3;
    const int quad = n & 7;
    const uint4 mv = *reinterpret_cast<const uint4*>(
        mask + ((size_t)(bx * 256 + row) * (NN / 8)) + jq * 128 + quad * 16);
    *reinterpret_cast<uint4*>(&mk[row * 36 + quad * 4]) = mv;
  }
  {
    const uint4 s0 = *reinterpret_cast<const uint4*>(wsrc + (size_t)r0 * NN + un * 8);
    const uint4 s1 = *reinterpret_cast<const uint4*>(wsrc + (size_t)(r0 + 32) * NN + un * 8);
    *reinterpret_cast<uint4*>(&wt[0][r0 * 128 + up * 8]) = s0;
    *reinterpret_cast<uint4*>(&wt[0][(r0 + 32) * 128 + up * 8]) = s1;
  }
  __syncthreads();

  f32x4 acc0[4] = {}, acc1[4] = {};
  f32x4 accs0 = {}, accs1 = {};
  short8 ones;
#pragma unroll
  for (int e = 0; e < 8; ++e) ones[e] = (short)0x3F80;

  int buf = 0;
  for (int tile = 0; tile < 8; ++tile) {
    uint4 n0, n1;
    const bool pf = (tile < 7);
    if (pf) {
      n0 = *reinterpret_cast<const uint4*>(
          wsrc + (size_t)r0 * NN + (tile + 1) * 128 + un * 8);
      n1 = *reinterpret_cast<const uint4*>(
          wsrc + (size_t)(r0 + 32) * NN + (tile + 1) * 128 + un * 8);
    }

    const uint4 mq0 = *reinterpret_cast<const uint4*>(
        &mk[(wv * 32 + rloc) * 36 + tile * 4]);
    const uint4 mq1 = *reinterpret_cast<const uint4*>(
        &mk[(wv * 32 + 16 + rloc) * 36 + tile * 4]);
#pragma unroll
    for (int ks = 0; ks < 4; ++ks) {
      short8 bfr[4];
#pragma unroll
      for (int dt = 0; dt < 4; ++dt) {
        const int row = dt * 16 + rloc;
        const int unit = (ks * 4 + g) ^ (row & 7);
        bfr[dt] = *reinterpret_cast<const short8*>(&wt[buf][row * 128 + unit * 8]);
      }
      const int jloc = tile * 128 + ks * 32 + g * 8;
      const float4 d0 = *reinterpret_cast<const float4*>(dg + jloc);
      const float4 d1 = *reinterpret_cast<const float4*>(dg + jloc + 4);
      const float dvv[8] = {d0.x, d0.y, d0.z, d0.w, d1.x, d1.y, d1.z, d1.w};
      const u32 mw0 = (ks == 0) ? mq0.x : (ks == 1) ? mq0.y : (ks == 2) ? mq0.z : mq0.w;
      const u32 mw1 = (ks == 0) ? mq1.x : (ks == 1) ? mq1.y : (ks == 2) ? mq1.z : mq1.w;
      const u32 mb0 = (mw0 >> (g * 8)) & 0xffu;
      const u32 mb1 = (mw1 >> (g * 8)) & 0xffu;
      short8 af0, af1;
#pragma unroll
      for (int e = 0; e < 8; ++e) {
        const float dj = dvv[e];
        float x0 = fmaxf(sa0 + dj, fmaf(NEG_SLOPE, dj, sb0));
        float x1 = fmaxf(sa1 + dj, fmaf(NEG_SLOPE, dj, sb1));
        x0 = (mb0 & (1u << e)) ? x0 : -400.f;
        x1 = (mb1 & (1u << e)) ? x1 : -400.f;
        float p0, p1;
        asm("v_exp_f32 %0, %1" : "=v"(p0) : "v"(x0));
        asm("v_exp_f32 %0, %1" : "=v"(p1) : "v"(x1));
        __hip_bfloat16 b0 = __float2bfloat16(p0);
        __hip_bfloat16 b1 = __float2bfloat16(p1);
        af0[e] = *reinterpret_cast<const short*>(&b0);
        af1[e] = *reinterpret_cast<const short*>(&b1);
      }
#pragma unroll
      for (int dt = 0; dt < 4; ++dt) {
        acc0[dt] = __builtin_amdgcn_mfma_f32_16x16x32_bf16(af0, bfr[dt], acc0[dt], 0, 0, 0);
        acc1[dt] = __builtin_amdgcn_mfma_f32_16x16x32_bf16(af1, bfr[dt], acc1[dt], 0, 0, 0);
      }
      accs0 = __builtin_amdgcn_mfma_f32_16x16x32_bf16(af0, ones, accs0, 0, 0, 0);
      accs1 = __builtin_amdgcn_mfma_f32_16x16x32_bf16(af1, ones, accs1, 0, 0, 0);
    }

    if (pf) {
      *reinterpret_cast<uint4*>(&wt[buf ^ 1][r0 * 128 + up * 8]) = n0;
      *reinterpret_cast<uint4*>(&wt[buf ^ 1][(r0 + 32) * 128 + up * 8]) = n1;
    }
    __syncthreads();
    buf ^= 1;
  }

  // ---- write partials ----
  u16* Pb = Pp + (size_t)jq * NN * OUT_DIM;
#pragma unroll
  for (int dt = 0; dt < 4; ++dt)
#pragma unroll
    for (int q = 0; q < 4; ++q) {
      __hip_bfloat16 v0 = __float2bfloat16(acc0[dt][q]);
      __hip_bfloat16 v1 = __float2bfloat16(acc1[dt][q]);
      Pb[(size_t)(i_base + g * 4 + q) * OUT_DIM + h * HD + dt * 16 + rloc] =
          *reinterpret_cast<const u16*>(&v0);
      Pb[(size_t)(i_base + 16 + g * 4 + q) * OUT_DIM + h * HD + dt * 16 + rloc] =
          *reinterpret_cast<const u16*>(&v1);
    }
  if (rloc == 0) {
    *reinterpret_cast<f32x4*>(&Sp[((size_t)jq * NH + h) * NN + i_base + g * 4]) = accs0;
    *reinterpret_cast<f32x4*>(&Sp[((size_t)jq * NH + h) * NN + i_base + 16 + g * 4]) = accs1;
  }

  // ---- last-block merge (rocPRIM pattern): 16 blocks per i-tile bx ----
  __syncthreads();      // all stores of this block retired (waitcnt before barrier)
  if (t == 0) {
    __threadfence();    // release: flush this XCD's L2
    const int prev = atomicAdd(cnt + bx, 1);
    last_flag = (prev == 15);
  }
  __syncthreads();
  if (!last_flag) return;
  __threadfence();      // acquire: invalidate stale caches before reading partials

  {
    const int c0 = lane * 4;
    const int hh = lane >> 4;
    const float4 gm = *reinterpret_cast<const float4*>(gamma + c0);
    const float4 bt = *reinterpret_cast<const float4*>(beta + c0);
    for (int rr = 0; rr < 32; ++rr) {
      const int i = bx * 256 + wv * 32 + rr;
      float v[4] = {0.f, 0.f, 0.f, 0.f};
      float denom = 0.f;
#pragma unroll
      for (int q = 0; q < 4; ++q) {
        const ushort4 pv = *reinterpret_cast<const ushort4*>(
            Pp + (size_t)q * NN * OUT_DIM + (size_t)i * OUT_DIM + c0);
        v[0] += __uint_as_float((u32)pv.x << 16);
        v[1] += __uint_as_float((u32)pv.y << 16);
        v[2] += __uint_as_float((u32)pv.z << 16);
        v[3] += __uint_as_float((u32)pv.w << 16);
        denom += Sp[((size_t)q * NH + hh) * NN + i];
      }
      const float inv = 1.f / denom;
      float sum = 0.f, sq = 0.f;
#pragma unroll
      for (int q2 = 0; q2 < 4; ++q2) {
        float xx = v[q2] * inv;
        xx = (xx > 0.f) ? xx : expm1f(xx);
        v[q2] = xx;
        sum += xx;
        sq += xx * xx;
      }
#pragma unroll
      for (int mm = 32; mm >= 1; mm >>= 1) {
        sum += __shfl_xor(sum, mm);
        sq += __shfl_xor(sq, mm);
      }
      const float mu = sum * (1.f / OUT_DIM);
      const float var = sq * (1.f / OUT_DIM) - mu * mu;
      const float rs = rsqrtf(var + LN_EPS);
      float4 o;
      o.x = (v[0] - mu) * rs * gm.x + bt.x;
      o.y = (v[1] - mu) * rs * gm.y + bt.y;
      o.z = (v[2] - mu) * rs * gm.z + bt.z;
      o.w = (v[3] - mu) * rs * gm.w + bt.w;
      *reinterpret_cast<float4*>(out + (size_t)i * OUT_DIM + c0) = o;
    }
  }
}

extern "C" void kernel_launch(void* const* d_in, const int* in_sizes, int n_in,
                              void* d_out, int out_size, void* d_ws, size_t ws_size,
                              hipStream_t stream) {
  const float* x = (const float*)d_in[0];
  const int* adj = (const int*)d_in[1];
  const float* W = (const float*)d_in[2];
  const float* a = (const float*)d_in[3];
  const float* gamma = (const float*)d_in[4];
  const float* beta = (const float*)d_in[5];
  float* out = (float*)d_out;

  char* ws = (char*)d_ws;
  size_t off = 0;
  u16* WxT = (u16*)(ws + off);        off += (size_t)NH * HD * NN * 2;          // 2 MiB
  float* s_src = (float*)(ws + off);  off += (size_t)NH * NN * 4;               // 64 KiB
  float* d_dst = (float*)(ws + off);  off += (size_t)NH * NN * 4;               // 64 KiB
  u32* maxd_u = (u32*)(ws + off);     off += 256;
  int* cnt = (int*)(ws + off);        off += 256;
  u8* mask = (u8*)(ws + off);         off += (size_t)NN * (NN / 8);             // 2 MiB
  u16* Pp = (u16*)(ws + off);         off += (size_t)4 * NN * OUT_DIM * 2;      // 8 MiB (bf16)
  float* Sp = (float*)(ws + off);     off += (size_t)4 * NH * NN * 4;           // 256 KiB
  u16* Wt = (u16*)(ws + off);         off += (size_t)NH * HD * IN_DIM * 2;      // 256 KiB

  k0_pack<<<dim3(512), dim3(1024), 0, stream>>>(adj, mask, W, Wt, maxd_u, cnt);
  k1_proj<<<dim3(256), dim3(512), 0, stream>>>(x, Wt, a, WxT, s_src, d_dst, maxd_u);
  k3_attn<<<dim3(16, NH, 4), dim3(512), 0, stream>>>(mask, WxT, s_src, d_dst,
                                                     maxd_u, Pp, Sp,
                                                     gamma, beta, out, cnt);
}

// Round 12
// 65.003 us; speedup vs baseline: 2.2648x; 2.2648x over previous
//
#include <hip/hip_runtime.h>
#include <hip/hip_bf16.h>

#define NN 4096
#define IN_DIM 512
#define OUT_DIM 256
#define NH 4
#define HD 64
#define NEG_SLOPE 0.2f
#define LN_EPS 1e-5f
#define LOG2E 1.4426950408889634f

typedef __attribute__((ext_vector_type(8))) short short8;
typedef __attribute__((ext_vector_type(4))) float f32x4;
typedef unsigned short u16;
typedef unsigned int u32;
typedef unsigned char u8;

// ---------------------------------------------------------------------------
// K0: pack (adj>0)|I into bitmask [NN][NN/8 B]; blocks < 128 also transpose
// W [H][K][D] f32 -> Wt [h*64+d][512] bf16.   [round-7 verified]
// ---------------------------------------------------------------------------
__global__ __launch_bounds__(1024) void k0_pack(
    const int* __restrict__ adj, u8* __restrict__ mask,
    const float* __restrict__ W, u16* __restrict__ Wt)
{
  const int b = blockIdx.x;
  const int t = threadIdx.x;
#pragma unroll
  for (int it = 0; it < 4; ++it) {
    const int row = b * 8 + it * 2 + (t >> 9);
    const int byte = t & 511;
    const int j0 = byte * 8;
    const int4 v0 = *reinterpret_cast<const int4*>(adj + (size_t)row * NN + j0);
    const int4 v1 = *reinterpret_cast<const int4*>(adj + (size_t)row * NN + j0 + 4);
    const int vv[8] = {v0.x, v0.y, v0.z, v0.w, v1.x, v1.y, v1.z, v1.w};
    u32 bbits = 0;
#pragma unroll
    for (int c = 0; c < 8; ++c)
      if ((vv[c] > 0) || (row == j0 + c)) bbits |= (1u << c);
    mask[(size_t)row * (NN / 8) + byte] = (u8)bbits;
  }
  if (b < 128) {
    const int n = b * 1024 + t;      // n = h*2^15 + k*2^6 + d
    const int d = n & 63;
    const int k = (n >> 6) & 511;
    const int h = n >> 15;
    __hip_bfloat16 bv = __float2bfloat16(W[n]);
    Wt[(size_t)(h * HD + d) * IN_DIM + k] = *reinterpret_cast<const u16*>(&bv);
  }
}

// ---------------------------------------------------------------------------
// K1: MFMA projection. grid 256 (16-row tiles), block 256 = 4 waves (wave=head).
// [round-7 verified, measured-best]
// ---------------------------------------------------------------------------
__global__ __launch_bounds__(256, 4) void k1_proj(
    const float* __restrict__ x, const u16* __restrict__ Wt,
    const float* __restrict__ a,
    u16* __restrict__ WxT,
    float* __restrict__ s_src,
    float* __restrict__ d_dst)
{
  const int i0 = blockIdx.x * 16;
  const int t = threadIdx.x;
  const int h = t >> 6;          // wave = head
  const int lane = t & 63;
  const int rloc = lane & 15;
  const int g = lane >> 4;

  __shared__ u16 xl[16 * 512];   // [row][unit*8], units XOR-swizzled by row&7

  {
    const int r = t >> 4;
    const int ug = t & 15;
    const float* xr = x + (size_t)(i0 + r) * IN_DIM + ug * 32;
#pragma unroll
    for (int jj = 0; jj < 4; ++jj) {
      const float4 lo = *reinterpret_cast<const float4*>(xr + jj * 8);
      const float4 hi = *reinterpret_cast<const float4*>(xr + jj * 8 + 4);
      const float fv[8] = {lo.x, lo.y, lo.z, lo.w, hi.x, hi.y, hi.z, hi.w};
      u16 us[8];
#pragma unroll
      for (int e = 0; e < 8; ++e) {
        __hip_bfloat16 bv = __float2bfloat16(fv[e]);
        us[e] = *reinterpret_cast<const u16*>(&bv);
      }
      const int u = ug * 4 + jj;
      const int phys = (u & 56) | ((u & 7) ^ (r & 7));
      uint4 pk;
      pk.x = (u32)us[0] | ((u32)us[1] << 16);
      pk.y = (u32)us[2] | ((u32)us[3] << 16);
      pk.z = (u32)us[4] | ((u32)us[5] << 16);
      pk.w = (u32)us[6] | ((u32)us[7] << 16);
      *reinterpret_cast<uint4*>(&xl[r * 512 + phys * 8]) = pk;
    }
  }
  __syncthreads();

  f32x4 acc[4] = {};
  const u16* wb = Wt + (size_t)(h * HD + rloc) * IN_DIM;
#pragma unroll
  for (int ks = 0; ks < 16; ++ks) {
    const int u = ks * 4 + g;
    const int phys = (u & 56) | ((u & 7) ^ (rloc & 7));
    const short8 af = *reinterpret_cast<const short8*>(&xl[rloc * 512 + phys * 8]);
#pragma unroll
    for (int dt = 0; dt < 4; ++dt) {
      const short8 bf = *reinterpret_cast<const short8*>(
          wb + (size_t)dt * 16 * IN_DIM + ks * 32 + g * 8);
      acc[dt] = __builtin_amdgcn_mfma_f32_16x16x32_bf16(af, bf, acc[dt], 0, 0, 0);
    }
  }

#pragma unroll
  for (int dt = 0; dt < 4; ++dt) {
    u16 us[4];
#pragma unroll
    for (int q = 0; q < 4; ++q) {
      __hip_bfloat16 bv = __float2bfloat16(acc[dt][q]);
      us[q] = *reinterpret_cast<const u16*>(&bv);
    }
    ushort4 pk = {us[0], us[1], us[2], us[3]};
    *reinterpret_cast<ushort4*>(
        WxT + (size_t)(h * HD + dt * 16 + rloc) * NN + i0 + g * 4) = pk;
  }

  float as_v[4], ad_v[4];
#pragma unroll
  for (int dt = 0; dt < 4; ++dt) {
    as_v[dt] = a[(size_t)h * 2 * HD + dt * 16 + rloc];
    ad_v[dt] = a[(size_t)h * 2 * HD + HD + dt * 16 + rloc];
  }
  float sv[4], dv[4];
#pragma unroll
  for (int q = 0; q < 4; ++q) {
    float s = 0.f, d = 0.f;
#pragma unroll
    for (int dt = 0; dt < 4; ++dt) {
      s = fmaf(acc[dt][q], as_v[dt], s);
      d = fmaf(acc[dt][q], ad_v[dt], d);
    }
    sv[q] = s; dv[q] = d;
  }
#pragma unroll
  for (int mm = 8; mm >= 1; mm >>= 1) {
#pragma unroll
    for (int q = 0; q < 4; ++q) {
      sv[q] += __shfl_xor(sv[q], mm);
      dv[q] += __shfl_xor(dv[q], mm);
    }
  }
  if (rloc == 0) {
#pragma unroll
    for (int q = 0; q < 4; ++q) {
      const int i = i0 + g * 4 + q;
      s_src[(size_t)h * NN + i] = sv[q] * LOG2E;
      d_dst[(size_t)h * NN + i] = dv[q] * LOG2E;
    }
  }
}

// ---------------------------------------------------------------------------
// K2: maxd[h] = max_j d (log2 domain) AND E-tables:
// E12[h][j] = (exp2(dj), exp2(0.2*dj)). grid 4, block 1024.
// ---------------------------------------------------------------------------
__global__ __launch_bounds__(1024) void k2_prep(
    const float* __restrict__ d_dst, float* __restrict__ maxd,
    float2* __restrict__ E12)
{
  __shared__ float red[16];
  const int h = blockIdx.x;
  const int t = threadIdx.x;
  float mx = -3.4e38f;
#pragma unroll
  for (int p = 0; p < 4; ++p) {
    const int j = p * 1024 + t;
    const float dj = d_dst[(size_t)h * NN + j];
    mx = fmaxf(mx, dj);
    const float djs = dj * NEG_SLOPE;
    float e1, e2;
    asm("v_exp_f32 %0, %1" : "=v"(e1) : "v"(dj));    // 2^dj
    asm("v_exp_f32 %0, %1" : "=v"(e2) : "v"(djs));   // 2^(0.2 dj)
    E12[(size_t)h * NN + j] = make_float2(e1, e2);
  }
#pragma unroll
  for (int mm = 32; mm >= 1; mm >>= 1) mx = fmaxf(mx, __shfl_xor(mx, mm));
  if ((t & 63) == 0) red[t >> 6] = mx;
  __syncthreads();
  if (t == 0) {
    float m2 = red[0];
#pragma unroll
    for (int q = 1; q < 16; ++q) m2 = fmaxf(m2, red[q]);
    maxd[h] = m2;
  }
}

// ---------------------------------------------------------------------------
// K3: masked rank-1 softmax via E-tables (NO exp in inner loop) + PV (bf16
// MFMA), LDS-staged & double-buffered. grid (16 i-blocks, 4 heads,
// 4 j-quarters), block 512 = 8 waves x 32 rows. [round-7 geometry]
// p = max(c1*E1[j], c2*E2[j]); c1,c2 per-row (2 exp in prologue).
// ---------------------------------------------------------------------------
__global__ __launch_bounds__(512) void k3_attn(
    const u8* __restrict__ mask,
    const u16* __restrict__ WxT,
    const float* __restrict__ s_src, const float* __restrict__ maxd,
    const float2* __restrict__ E12,
    u16* __restrict__ Pp, float* __restrict__ Sp)
{
  const int bx = blockIdx.x;
  const int h = blockIdx.y;
  const int jq = blockIdx.z;
  const int t = threadIdx.x;
  const int wv = t >> 6;
  const int lane = t & 63;
  const int rloc = lane & 15;
  const int g = lane >> 4;
  const int i_base = bx * 256 + wv * 32;

  __shared__ u16 wt[2][64 * 128];   // [buf][row*128 + unit*8], XOR-swizzled
  __shared__ u32 mk[256 * 36];      // [row][36 words] (32 used, pad 4)

  const float md = maxd[h];
  const float si0 = s_src[(size_t)h * NN + i_base + rloc];
  const float si1 = s_src[(size_t)h * NN + i_base + 16 + rloc];
  const float e00 = si0 + md, e01 = si1 + md;
  const float m0 = fmaxf(e00, NEG_SLOPE * e00);
  const float m1 = fmaxf(e01, NEG_SLOPE * e01);
  const float sa0 = si0 - m0, sb0 = fmaf(NEG_SLOPE, si0, -m0);
  const float sa1 = si1 - m1, sb1 = fmaf(NEG_SLOPE, si1, -m1);
  float c1_0, c2_0, c1_1, c2_1;
  asm("v_exp_f32 %0, %1" : "=v"(c1_0) : "v"(sa0));
  asm("v_exp_f32 %0, %1" : "=v"(c2_0) : "v"(sb0));
  asm("v_exp_f32 %0, %1" : "=v"(c1_1) : "v"(sa1));
  asm("v_exp_f32 %0, %1" : "=v"(c2_1) : "v"(sb1));

  const float* eg = reinterpret_cast<const float*>(E12 + (size_t)h * NN + jq * 1024);
  const u16* wsrc = WxT + (size_t)(h * HD) * NN + jq * 1024;

  const int r0 = t >> 4;
  const int un = t & 15;
  const int up = un ^ (r0 & 7);

#pragma unroll
  for (int k = 0; k < 4; ++k) {
    const int n = k * 512 + t;
    const int row = n >> 3;
    const int quad = n & 7;
    const uint4 mv = *reinterpret_cast<const uint4*>(
        mask + ((size_t)(bx * 256 + row) * (NN / 8)) + jq * 128 + quad * 16);
    *reinterpret_cast<uint4*>(&mk[row * 36 + quad * 4]) = mv;
  }
  {
    const uint4 s0 = *reinterpret_cast<const uint4*>(wsrc + (size_t)r0 * NN + un * 8);
    const uint4 s1 = *reinterpret_cast<const uint4*>(wsrc + (size_t)(r0 + 32) * NN + un * 8);
    *reinterpret_cast<uint4*>(&wt[0][r0 * 128 + up * 8]) = s0;
    *reinterpret_cast<uint4*>(&wt[0][(r0 + 32) * 128 + up * 8]) = s1;
  }
  __syncthreads();

  f32x4 acc0[4] = {}, acc1[4] = {};
  f32x4 accs0 = {}, accs1 = {};
  short8 ones;
#pragma unroll
  for (int e = 0; e < 8; ++e) ones[e] = (short)0x3F80;

  int buf = 0;
  for (int tile = 0; tile < 8; ++tile) {
    uint4 n0, n1;
    const bool pf = (tile < 7);
    if (pf) {
      n0 = *reinterpret_cast<const uint4*>(
          wsrc + (size_t)r0 * NN + (tile + 1) * 128 + un * 8);
      n1 = *reinterpret_cast<const uint4*>(
          wsrc + (size_t)(r0 + 32) * NN + (tile + 1) * 128 + un * 8);
    }

    const uint4 mq0 = *reinterpret_cast<const uint4*>(
        &mk[(wv * 32 + rloc) * 36 + tile * 4]);
    const uint4 mq1 = *reinterpret_cast<const uint4*>(
        &mk[(wv * 32 + 16 + rloc) * 36 + tile * 4]);
#pragma unroll
    for (int ks = 0; ks < 4; ++ks) {
      short8 bfr[4];
#pragma unroll
      for (int dt = 0; dt < 4; ++dt) {
        const int row = dt * 16 + rloc;
        const int unit = (ks * 4 + g) ^ (row & 7);
        bfr[dt] = *reinterpret_cast<const short8*>(&wt[buf][row * 128 + unit * 8]);
      }
      const int jloc = tile * 128 + ks * 32 + g * 8;
      const float* eb = eg + 2 * jloc;
      const float4 Ea = *reinterpret_cast<const float4*>(eb);
      const float4 Eb = *reinterpret_cast<const float4*>(eb + 4);
      const float4 Ec = *reinterpret_cast<const float4*>(eb + 8);
      const float4 Ed = *reinterpret_cast<const float4*>(eb + 12);
      const float E1v[8] = {Ea.x, Ea.z, Eb.x, Eb.z, Ec.x, Ec.z, Ed.x, Ed.z};
      const float E2v[8] = {Ea.y, Ea.w, Eb.y, Eb.w, Ec.y, Ec.w, Ed.y, Ed.w};
      const u32 mw0 = (ks == 0) ? mq0.x : (ks == 1) ? mq0.y : (ks == 2) ? mq0.z : mq0.w;
      const u32 mw1 = (ks == 0) ? mq1.x : (ks == 1) ? mq1.y : (ks == 2) ? mq1.z : mq1.w;
      const u32 mb0 = (mw0 >> (g * 8)) & 0xffu;
      const u32 mb1 = (mw1 >> (g * 8)) & 0xffu;
      short8 af0, af1;
#pragma unroll
      for (int e = 0; e < 8; ++e) {
        float p0 = fmaxf(c1_0 * E1v[e], c2_0 * E2v[e]);
        float p1 = fmaxf(c1_1 * E1v[e], c2_1 * E2v[e]);
        p0 = (mb0 & (1u << e)) ? p0 : 0.f;
        p1 = (mb1 & (1u << e)) ? p1 : 0.f;
        __hip_bfloat16 b0 = __float2bfloat16(p0);
        __hip_bfloat16 b1 = __float2bfloat16(p1);
        af0[e] = *reinterpret_cast<const short*>(&b0);
        af1[e] = *reinterpret_cast<const short*>(&b1);
      }
#pragma unroll
      for (int dt = 0; dt < 4; ++dt) {
        acc0[dt] = __builtin_amdgcn_mfma_f32_16x16x32_bf16(af0, bfr[dt], acc0[dt], 0, 0, 0);
        acc1[dt] = __builtin_amdgcn_mfma_f32_16x16x32_bf16(af1, bfr[dt], acc1[dt], 0, 0, 0);
      }
      accs0 = __builtin_amdgcn_mfma_f32_16x16x32_bf16(af0, ones, accs0, 0, 0, 0);
      accs1 = __builtin_amdgcn_mfma_f32_16x16x32_bf16(af1, ones, accs1, 0, 0, 0);
    }

    if (pf) {
      *reinterpret_cast<uint4*>(&wt[buf ^ 1][r0 * 128 + up * 8]) = n0;
      *reinterpret_cast<uint4*>(&wt[buf ^ 1][(r0 + 32) * 128 + up * 8]) = n1;
    }
    __syncthreads();
    buf ^= 1;
  }

  u16* Pb = Pp + (size_t)jq * NN * OUT_DIM;
#pragma unroll
  for (int dt = 0; dt < 4; ++dt)
#pragma unroll
    for (int q = 0; q < 4; ++q) {
      __hip_bfloat16 v0 = __float2bfloat16(acc0[dt][q]);
      __hip_bfloat16 v1 = __float2bfloat16(acc1[dt][q]);
      Pb[(size_t)(i_base + g * 4 + q) * OUT_DIM + h * HD + dt * 16 + rloc] =
          *reinterpret_cast<const u16*>(&v0);
      Pb[(size_t)(i_base + 16 + g * 4 + q) * OUT_DIM + h * HD + dt * 16 + rloc] =
          *reinterpret_cast<const u16*>(&v1);
    }
  if (rloc == 0) {
    *reinterpret_cast<f32x4*>(&Sp[((size_t)jq * NH + h) * NN + i_base + g * 4]) = accs0;
    *reinterpret_cast<f32x4*>(&Sp[((size_t)jq * NH + h) * NN + i_base + 16 + g * 4]) = accs1;
  }
}

// ---------------------------------------------------------------------------
// K4: merge 4 j-quarter partials, normalize, ELU, LayerNorm, store.
// [round-7 verified]
// ---------------------------------------------------------------------------
__global__ __launch_bounds__(256) void k4_final(
    const u16* __restrict__ Pp, const float* __restrict__ Sp,
    const float* __restrict__ gamma, const float* __restrict__ beta,
    float* __restrict__ out)
{
  const int i0 = blockIdx.x * 16;
  const int t = threadIdx.x;
  const int wv = t >> 6;
  const int lane = t & 63;
  const int c0 = lane * 4;
  const int h = lane >> 4;

  const float4 gm = *reinterpret_cast<const float4*>(gamma + c0);
  const float4 bt = *reinterpret_cast<const float4*>(beta + c0);

  for (int rr = 0; rr < 4; ++rr) {
    const int i = i0 + wv * 4 + rr;
    float v[4] = {0.f, 0.f, 0.f, 0.f};
    float denom = 0.f;
#pragma unroll
    for (int q = 0; q < 4; ++q) {
      const ushort4 pv = *reinterpret_cast<const ushort4*>(
          Pp + (size_t)q * NN * OUT_DIM + (size_t)i * OUT_DIM + c0);
      v[0] += __uint_as_float((u32)pv.x << 16);
      v[1] += __uint_as_float((u32)pv.y << 16);
      v[2] += __uint_as_float((u32)pv.z << 16);
      v[3] += __uint_as_float((u32)pv.w << 16);
      denom += Sp[((size_t)q * NH + h) * NN + i];
    }
    const float inv = 1.f / denom;
    float sum = 0.f, sq = 0.f;
#pragma unroll
    for (int q2 = 0; q2 < 4; ++q2) {
      float xx = v[q2] * inv;
      xx = (xx > 0.f) ? xx : expm1f(xx);
      v[q2] = xx;
      sum += xx;
      sq += xx * xx;
    }
#pragma unroll
    for (int mm = 32; mm >= 1; mm >>= 1) {
      sum += __shfl_xor(sum, mm);
      sq += __shfl_xor(sq, mm);
    }
    const float mu = sum * (1.f / OUT_DIM);
    const float var = sq * (1.f / OUT_DIM) - mu * mu;
    const float rs = rsqrtf(var + LN_EPS);
    float4 o;
    o.x = (v[0] - mu) * rs * gm.x + bt.x;
    o.y = (v[1] - mu) * rs * gm.y + bt.y;
    o.z = (v[2] - mu) * rs * gm.z + bt.z;
    o.w = (v[3] - mu) * rs * gm.w + bt.w;
    *reinterpret_cast<float4*>(out + (size_t)i * OUT_DIM + c0) = o;
  }
}

extern "C" void kernel_launch(void* const* d_in, const int* in_sizes, int n_in,
                              void* d_out, int out_size, void* d_ws, size_t ws_size,
                              hipStream_t stream) {
  const float* x = (const float*)d_in[0];
  const int* adj = (const int*)d_in[1];
  const float* W = (const float*)d_in[2];
  const float* a = (const float*)d_in[3];
  const float* gamma = (const float*)d_in[4];
  const float* beta = (const float*)d_in[5];
  float* out = (float*)d_out;

  char* ws = (char*)d_ws;
  size_t off = 0;
  u16* WxT = (u16*)(ws + off);        off += (size_t)NH * HD * NN * 2;          // 2 MiB
  float* s_src = (float*)(ws + off);  off += (size_t)NH * NN * 4;               // 64 KiB
  float* d_dst = (float*)(ws + off);  off += (size_t)NH * NN * 4;               // 64 KiB
  float* maxd = (float*)(ws + off);   off += 256;
  u8* mask = (u8*)(ws + off);         off += (size_t)NN * (NN / 8);             // 2 MiB
  u16* Pp = (u16*)(ws + off);         off += (size_t)4 * NN * OUT_DIM * 2;      // 8 MiB (bf16)
  float* Sp = (float*)(ws + off);     off += (size_t)4 * NH * NN * 4;           // 256 KiB
  u16* Wt = (u16*)(ws + off);         off += (size_t)NH * HD * IN_DIM * 2;      // 256 KiB
  float2* E12 = (float2*)(ws + off);  off += (size_t)NH * NN * 8;               // 128 KiB

  k0_pack<<<dim3(512), dim3(1024), 0, stream>>>(adj, mask, W, Wt);
  k1_proj<<<dim3(256), dim3(256), 0, stream>>>(x, Wt, a, WxT, s_src, d_dst);
  k2_prep<<<dim3(NH), dim3(1024), 0, stream>>>(d_dst, maxd, E12);
  k3_attn<<<dim3(16, NH, 4), dim3(512), 0, stream>>>(mask, WxT, s_src, maxd,
                                                     E12, Pp, Sp);
  k4_final<<<dim3(256), dim3(256), 0, stream>>>(Pp, Sp, gamma, beta, out);
}